// Round 1
// baseline (115.653 us; speedup 1.0000x reference)
//
#include <hip/hip_runtime.h>
#include <stdint.h>

// Problem constants
#define D    10000   // hypervector dimensions
#define P    784     // pixels
#define B    32      // batch
#define NL   1000    // levels
#define NC   10      // classes

#define ROWW 320           // padded words per packed row (320*32 = 10240 bits >= 10000)
#define ROWB (ROWW * 4)    // 1280 bytes per packed row
#define NW   313           // valid words (ceil(10000/32))

#define CHUNKS 16
#define PLEN   49          // P / CHUNKS
#define PLANES 6           // per-chunk counts <= 49 < 64

// ws layout (bytes)
#define LVL_OFF  0
#define POS_OFF  (NL * ROWB)             // +1,280,000

#define PACK_BPR 10        // blocks per packed row: 256 thr * 4 dims = 1024; 10*1024 = 10240

// ------- kernel 1: pack sign bits of level & pos (bit=1 means -1) + out-zero --------
__global__ void k_pack(const float* __restrict__ lvl, const float* __restrict__ pos,
                       uint32_t* __restrict__ lvl_b, uint32_t* __restrict__ pos_b,
                       float* __restrict__ out) {
    int bx  = blockIdx.x;
    int row = bx / PACK_BPR;
    int seg = bx % PACK_BPR;
    int d0  = seg * 1024 + threadIdx.x * 4;          // each lane: 4 consecutive dims
    const float* src; uint32_t* dst;
    if (row < NL) { src = lvl + (size_t)row * D;        dst = lvl_b + (size_t)row * ROWW; }
    else          { src = pos + (size_t)(row - NL) * D; dst = pos_b + (size_t)(row - NL) * ROWW; }

    uint32_t nib = 0;
    if (d0 < D) {                                    // D%4==0 -> full float4 or nothing
        float4 v = *(const float4*)(src + d0);
        nib = (v.x < 0.0f ? 1u : 0u) | (v.y < 0.0f ? 2u : 0u) |
              (v.z < 0.0f ? 4u : 0u) | (v.w < 0.0f ? 8u : 0u);
    }
    int lane = threadIdx.x & 63;
    uint32_t val = nib << ((lane & 7) * 4);          // word j <- lanes 8j..8j+7
    val |= __shfl_xor(val, 1, 64);
    val |= __shfl_xor(val, 2, 64);
    val |= __shfl_xor(val, 4, 64);
    if ((lane & 7) == 0) {
        int gword = (seg * 1024 + (threadIdx.x & ~7) * 4) >> 5;
        dst[gword] = val;                            // lanes 0,8,..: consecutive words
    }
    // zero logits (k_bindcls accumulates with atomics; stream orders k_pack first)
    if (bx < 2) {
        int i = bx * 256 + threadIdx.x;
        if (i < B * NC) out[i] = 0.0f;
    }
}

// ------- kernel 2: fused bind (XOR) + bundle (bit-sliced) + sign + classify ---------
template <int N>
__device__ inline void bsadd(const uint32_t* a, const uint32_t* b, uint32_t* s) {
    uint32_t cin = 0;
    #pragma unroll
    for (int k = 0; k < N; k++) {
        uint32_t t = a[k] ^ b[k];
        s[k] = t ^ cin;
        cin  = (a[k] & b[k]) | (cin & t);
    }
    s[N] = cin;
}

// grid = (5 word-segs, B), block = 1024 (16 waves; wave w handles pixel chunk w of 49)
__global__ __launch_bounds__(1024) void k_bindcls(const float* __restrict__ x,
                                                  const uint32_t* __restrict__ lvl_b,
                                                  const uint32_t* __restrict__ pos_b,
                                                  const float* __restrict__ cw,
                                                  float* __restrict__ out) {
    int b = blockIdx.y, seg = blockIdx.x;
    int tid  = threadIdx.x;
    int wave = tid >> 6, lane = tid & 63;
    int gw = seg * 64 + lane;                        // global word [0,320)

    __shared__ int      offs_l[P];                   // level-row byte offsets for batch b
    __shared__ uint32_t red[CHUNKS][PLANES][64];
    __shared__ uint32_t red2[4][8][64];
    __shared__ uint32_t minus_s[64];

    // compute level offsets from x directly (kills the global offs->gather 2-hop chain)
    if (tid < P) {
        float v = rintf(x[b * P + tid] * 999.0f);    // round-half-even == jnp.round
        v = fminf(fmaxf(v, 0.0f), 999.0f);
        offs_l[tid] = (int)v * ROWB;
    }
    __syncthreads();

    const uint32_t* pb = pos_b + (size_t)(wave * PLEN) * ROWW + gw;
    const char* lb = (const char*)lvl_b;
    int wb = gw << 2;
    const int* po = offs_l + wave * PLEN;            // LDS broadcast reads

    uint32_t pl[PLANES];
    #pragma unroll
    for (int k = 0; k < PLANES; k++) pl[k] = 0;

    #pragma unroll 8
    for (int i = 0; i + 1 < PLEN; i += 2) {          // 24 pair-iterations
        int o0 = po[i], o1 = po[i + 1];
        uint32_t l0 = *(const uint32_t*)(lb + o0 + wb);
        uint32_t l1 = *(const uint32_t*)(lb + o1 + wb);
        uint32_t x0 = l0 ^ pb[(size_t)i * ROWW];
        uint32_t x1 = l1 ^ pb[(size_t)(i + 1) * ROWW];
        uint32_t t  = x0 ^ x1;                       // CSA full-adder into bit-planes
        uint32_t cr = (x0 & x1) | (pl[0] & t);
        pl[0] ^= t;
        #pragma unroll
        for (int k = 1; k < PLANES; k++) { uint32_t tt = pl[k] & cr; pl[k] ^= cr; cr = tt; }
    }
    {   // tail pixel (PLEN is odd): increment planes by x0
        int o0 = po[PLEN - 1];
        uint32_t x0 = (*(const uint32_t*)(lb + o0 + wb)) ^ pb[(size_t)(PLEN - 1) * ROWW];
        uint32_t cr = x0;
        #pragma unroll
        for (int k = 0; k < PLANES; k++) { uint32_t tt = pl[k] & cr; pl[k] ^= cr; cr = tt; }
    }

    #pragma unroll
    for (int k = 0; k < PLANES; k++) red[wave][k][lane] = pl[k];
    __syncthreads();

    // stage B: waves 0..3 each combine 4 chunks -> 8-bit partial (<=196)
    if (wave < 4) {
        uint32_t ch[4][PLANES];
        #pragma unroll
        for (int c = 0; c < 4; c++)
            #pragma unroll
            for (int k = 0; k < PLANES; k++)
                ch[c][k] = red[wave * 4 + c][k][lane];
        uint32_t b1[7], b2[7], p8[8];
        bsadd<6>(ch[0], ch[1], b1);
        bsadd<6>(ch[2], ch[3], b2);
        bsadd<7>(b1, b2, p8);
        #pragma unroll
        for (int k = 0; k < 8; k++) red2[wave][k][lane] = p8[k];
    }
    __syncthreads();

    // stage C: wave 0 final combine + sign threshold
    if (wave == 0) {
        uint32_t q[4][8];
        #pragma unroll
        for (int c = 0; c < 4; c++)
            #pragma unroll
            for (int k = 0; k < 8; k++)
                q[c][k] = red2[c][k][lane];
        uint32_t t0[9], t1[9], s[10];
        bsadd<8>(q[0], q[1], t0);
        bsadd<8>(q[2], q[3], t1);
        bsadd<9>(t0, t1, s);
        // minus-mask: S >= 392  (carry-out of S + 632; 632 = bits {3,4,5,6,9})
        minus_s[lane] = s[9] | (s[8] & s[7] & (s[3] | s[4] | s[5] | s[6]));
    }
    __syncthreads();

    // classify: waves 0..4, wave k handles classes 2k, 2k+1
    if (wave < 5) {
        uint32_t minus = minus_s[lane];
        float sgn[32];
        #pragma unroll
        for (int j = 0; j < 32; j++) sgn[j] = ((minus >> j) & 1u) ? -1.0f : 1.0f;

        float a0 = 0.0f, a1 = 0.0f;
        int c0 = wave * 2;
        const float* r0 = cw + (size_t)c0 * D + gw * 32;
        const float* r1 = r0 + D;
        if (gw < NW - 1) {
            #pragma unroll
            for (int j = 0; j < 32; j++) { a0 = fmaf(sgn[j], r0[j], a0); a1 = fmaf(sgn[j], r1[j], a1); }
        } else if (gw == NW - 1) {                   // word 312: dims 9984..9999
            #pragma unroll
            for (int j = 0; j < 16; j++) { a0 = fmaf(sgn[j], r0[j], a0); a1 = fmaf(sgn[j], r1[j], a1); }
        }
        for (int o = 32; o > 0; o >>= 1) { a0 += __shfl_down(a0, o, 64); a1 += __shfl_down(a1, o, 64); }
        if (lane == 0) {
            atomicAdd(out + b * NC + c0,     a0);
            atomicAdd(out + b * NC + c0 + 1, a1);
        }
    }
}

extern "C" void kernel_launch(void* const* d_in, const int* in_sizes, int n_in,
                              void* d_out, int out_size, void* d_ws, size_t ws_size,
                              hipStream_t stream) {
    const float* x   = (const float*)d_in[0];   // [32,1,28,28]
    const float* pos = (const float*)d_in[1];   // [784,10000]
    const float* lvl = (const float*)d_in[2];   // [1000,10000]
    const float* cw  = (const float*)d_in[3];   // [10,10000]
    float* out = (float*)d_out;                 // [32,10]

    char* ws = (char*)d_ws;
    uint32_t*  lvl_b = (uint32_t*)(ws + LVL_OFF);
    uint32_t*  pos_b = (uint32_t*)(ws + POS_OFF);

    k_pack   <<<dim3((NL + P) * PACK_BPR), 256, 0, stream>>>(lvl, pos, lvl_b, pos_b, out);
    k_bindcls<<<dim3(5, B),               1024, 0, stream>>>(x, lvl_b, pos_b, cw, out);
}